// Round 6
// baseline (1209.063 us; speedup 1.0000x reference)
//
#include <hip/hip_runtime.h>
#include <hip/hip_bf16.h>

#define EMB 384
#define NPOS 8193   // 2L+1 state positions
#define LAYERS 12
#define BATCH 4

typedef __attribute__((ext_vector_type(8))) short bf16x8;
typedef __attribute__((ext_vector_type(4))) float f32x4;
typedef __attribute__((ext_vector_type(4))) unsigned short u16x4;

__device__ __forceinline__ float b2f(unsigned short u) {
    union { unsigned int i; float f; } v; v.i = ((unsigned int)u) << 16; return v.f;
}
__device__ __forceinline__ unsigned short f2b(float f) {
    union { float f; unsigned int i; } v; v.f = f;
    unsigned int x = v.i;
    return (unsigned short)((x + 0x7FFFu + ((x >> 16) & 1u)) >> 16);
}

// LDS plane0 tile: 768B rows, XOR bank swizzle (8x16B blocks keyed on row&7)
#define LDSOFF(row, inner) ((row) * 768 + ((inner) ^ (((row) & 7) << 4)))

// ---- weight pre-swizzle: W_swz[layer][kb(36)][nb(24)][lane(64)][8 bf16]
// logical K: 0..383 = w_center, 384..767 = w_right, 768..1151 = w_left
// per 16x32 block: lane holds col n = nb*16 + (lane&15), k = kb*32 + 8*(lane>>4) + e
__global__ void w_prep(const float* __restrict__ wl, const float* __restrict__ wc,
                       const float* __restrict__ wr, unsigned short* __restrict__ wswz) {
    int idx = blockIdx.x * blockDim.x + threadIdx.x;
    const int total = LAYERS * 36 * 24 * 64;
    if (idx >= total) return;
    int lane = idx & 63;
    int t = idx >> 6;
    int nb = t % 24; t /= 24;
    int kb = t % 36; t /= 36;
    int layer = t;
    int seg = kb / 12;
    const float* src = (seg == 0 ? wc : (seg == 1 ? wr : wl)) + (size_t)layer * EMB * EMB;
    int kloc = (kb % 12) * 32 + ((lane >> 4) << 3);
    int n = nb * 16 + (lane & 15);
    unsigned short o[8];
#pragma unroll
    for (int e = 0; e < 8; ++e) o[e] = f2b(src[(size_t)n * EMB + kloc + e]);
    *reinterpret_cast<uint4*>(wswz + (size_t)idx * 8) = *reinterpret_cast<uint4*>(o);
}

// ---- plane0 initial state, row-major X0[b][pos][384]
__global__ void x_init0(const float* __restrict__ embs, const float* __restrict__ mask,
                        unsigned short* __restrict__ X0) {
    int idx = blockIdx.x * blockDim.x + threadIdx.x;
    const int total = BATCH * NPOS * 48;
    if (idx >= total) return;
    int dg = idx % 48;
    int t = idx / 48;
    int pos = t % NPOS;
    int b = t / NPOS;
    int d0 = dg * 8;
    const float* m = mask + (size_t)b * EMB + d0;
    const float* src;
    if (pos >= 1 && pos <= 4096) src = embs + ((size_t)b * 4096 + (pos - 1)) * EMB + d0;
    else if (pos == 8192)        src = embs + (size_t)b * 4096 * EMB + d0;
    else                         src = m;
    unsigned short o[8];
#pragma unroll
    for (int e = 0; e < 8; ++e) o[e] = f2b(src[e]);
    *reinterpret_cast<uint4*>(X0 + ((size_t)b * NPOS + pos) * EMB + d0) = *reinterpret_cast<uint4*>(o);
}

// ---- plane1 initial state, fragment layout X1F[b][pblk(512)][kb(12)][lane(64)][8]
// pblk p covers positions 1+16p .. 16+16p; lane holds pos r=lane&15, k-sub g=lane>>4;
// elem e -> channel kb*32 + g*8 + e. Initial plane1 = mask (position-independent).
__global__ void x_init1(const float* __restrict__ mask, unsigned short* __restrict__ X1F) {
    int idx = blockIdx.x * blockDim.x + threadIdx.x;
    const int total = BATCH * 512 * 12 * 64;
    if (idx >= total) return;
    int lane = idx & 63;
    int t = idx >> 6;
    int kb = t % 12; t /= 12;
    int b = t / 512;
    int ch0 = kb * 32 + (lane >> 4) * 8;
    const float* m = mask + (size_t)b * EMB + ch0;
    unsigned short o[8];
#pragma unroll
    for (int e = 0; e < 8; ++e) o[e] = f2b(m[e]);
    *reinterpret_cast<uint4*>(X1F + (size_t)idx * 8) = *reinterpret_cast<uint4*>(o);
}

// ---- one layer, PT=64, 8 waves x (48 cols, 128 rows = 64pos x 2 planes)
// plane0 row-major via LDS (halo windows); plane1 fragment-layout via global (coalesced).
// Neighbor term plane-independent: computed once, copied.
__global__ __launch_bounds__(512, 4) void layer_k(
    const unsigned short* __restrict__ X0in, const unsigned short* __restrict__ X1in,
    unsigned short* __restrict__ X0out, unsigned short* __restrict__ X1out,
    const unsigned short* __restrict__ W, const float* __restrict__ bias) {
    __shared__ char smem[66 * 768];
    const int tid = threadIdx.x;
    const int b = blockIdx.y;
    const int bi = blockIdx.x;          // 0..127
    const int j0 = bi * 64;
    const size_t x0base = (size_t)b * NPOS * EMB;

    // stage plane0 rows pos j0..j0+65 (clamped)
    for (int idx = tid; idx < 66 * 48; idx += 512) {
        int row = idx / 48, cg = idx % 48;
        int pos = j0 + row; if (pos > 8192) pos = 8192;
        uint4 v = *reinterpret_cast<const uint4*>(X0in + x0base + (size_t)pos * EMB + cg * 8);
        *reinterpret_cast<uint4*>(smem + LDSOFF(row, cg * 16)) = v;
    }
    __syncthreads();

    const int lane = tid & 63;
    const int wv = tid >> 6;            // 0..7 n-slice
    const int nbase = wv * 48;
    const int lrow = lane & 15;
    const int g = lane >> 4;

    const unsigned short* x1base = X1in + ((size_t)b * 512 + 4 * bi) * 12 * 512;

    f32x4 a0[4][3], a1[4][3];
#pragma unroll
    for (int m = 0; m < 4; ++m)
#pragma unroll
        for (int n = 0; n < 3; ++n) a0[m][n] = f32x4{0.f, 0.f, 0.f, 0.f};

    const bf16x8* wb = reinterpret_cast<const bf16x8*>(W) + (size_t)(wv * 3) * 64 + lane;

    // ---- neighbor phase: kb 12..23 right (x0[p+2]), kb 24..35 left (x0[p]); plane0 rows
#pragma unroll
    for (int kb = 12; kb < 36; ++kb) {
        bf16x8 wf[3];
#pragma unroll
        for (int n = 0; n < 3; ++n) wf[n] = wb[(kb * 24 + n) * 64];
        const int d = (kb < 24) ? 2 : 0;
        const int byo = ((kb - 12) % 12) * 64 + g * 16;
#pragma unroll
        for (int m = 0; m < 4; ++m) {
            const int p = m * 16 + lrow;
            bf16x8 xf = *reinterpret_cast<const bf16x8*>(smem + LDSOFF(p + d, byo));
#pragma unroll
            for (int n = 0; n < 3; ++n)
                a0[m][n] = __builtin_amdgcn_mfma_f32_16x16x32_bf16(wf[n], xf, a0[m][n], 0, 0, 0);
        }
    }
    // copy plane-independent neighbor result to plane1 accumulators
#pragma unroll
    for (int m = 0; m < 4; ++m)
#pragma unroll
        for (int n = 0; n < 3; ++n) a1[m][n] = a0[m][n];

    // ---- center phase: kb 0..11; plane0 from LDS rows p+1, plane1 from fragment global
#pragma unroll
    for (int kb = 0; kb < 12; ++kb) {
        bf16x8 wf[3];
#pragma unroll
        for (int n = 0; n < 3; ++n) wf[n] = wb[(kb * 24 + n) * 64];
        const int byo = kb * 64 + g * 16;
#pragma unroll
        for (int m = 0; m < 4; ++m) {
            const int p = m * 16 + lrow;
            bf16x8 x0f = *reinterpret_cast<const bf16x8*>(smem + LDSOFF(p + 1, byo));
            bf16x8 x1f = *reinterpret_cast<const bf16x8*>(x1base + ((m * 12 + kb) << 9) + lane * 8);
#pragma unroll
            for (int n = 0; n < 3; ++n) {
                a0[m][n] = __builtin_amdgcn_mfma_f32_16x16x32_bf16(wf[n], x0f, a0[m][n], 0, 0, 0);
                a1[m][n] = __builtin_amdgcn_mfma_f32_16x16x32_bf16(wf[n], x1f, a1[m][n], 0, 0, 0);
            }
        }
    }

    // ---- epilogue: bias + relu + residual, both planes (all LDS/global reads pre-barrier)
#pragma unroll
    for (int m = 0; m < 4; ++m) {
        const int p = m * 16 + lrow;
#pragma unroll
        for (int n = 0; n < 3; ++n) {
            const int cb = nbase + n * 16 + g * 4;
            f32x4 bv = *reinterpret_cast<const f32x4*>(bias + cb);
            u16x4 r0 = *reinterpret_cast<const u16x4*>(smem + LDSOFF(p + 1, cb * 2));
            const int kbr = cb >> 5;
            const int l2r = ((cb & 31) >> 3) * 16 + lrow;
            u16x4 r1 = *reinterpret_cast<const u16x4*>(x1base + ((m * 12 + kbr) << 9) + l2r * 8 + (cb & 7));
#pragma unroll
            for (int ri = 0; ri < 4; ++ri) {
                a0[m][n][ri] = fmaxf(a0[m][n][ri] + bv[ri], 0.f) + b2f(r0[ri]);
                a1[m][n][ri] = fmaxf(a1[m][n][ri] + bv[ri], 0.f) + b2f(r1[ri]);
            }
        }
    }
    __syncthreads();

    // ---- plane0 out-tile (rows = local j, cols = channels)
#pragma unroll
    for (int m = 0; m < 4; ++m) {
        const int r = m * 16 + lrow;
#pragma unroll
        for (int n = 0; n < 3; ++n) {
            const int cb = nbase + n * 16 + g * 4;
            u16x4 o;
#pragma unroll
            for (int ri = 0; ri < 4; ++ri) o[ri] = f2b(a0[m][n][ri]);
            *reinterpret_cast<u16x4*>(smem + LDSOFF(r, cb * 2)) = o;
        }
    }
    __syncthreads();
    // scatter plane0 row-major with scramble permutation (+ dups at pt 0 / 8192)
    for (int idx = tid; idx < 64 * 48; idx += 512) {
        int rr = idx / 48, cg = idx % 48;
        int j = j0 + rr;
        if (j > 8190) continue;
        uint4 val = *reinterpret_cast<uint4*>(smem + LDSOFF(rr, cg * 16));
        int pt = (j & 1) ? ((j + NPOS) >> 1) : ((j >> 1) + 1);
        *reinterpret_cast<uint4*>(X0out + x0base + (size_t)pt * EMB + cg * 8) = val;
        if (j == 0)
            *reinterpret_cast<uint4*>(X0out + x0base + (size_t)8192 * EMB + cg * 8) = val;
        if (j == 8189)
            *reinterpret_cast<uint4*>(X0out + x0base + cg * 8) = val;
    }
    __syncthreads();

    // ---- plane1 out-tile
#pragma unroll
    for (int m = 0; m < 4; ++m) {
        const int r = m * 16 + lrow;
#pragma unroll
        for (int n = 0; n < 3; ++n) {
            const int cb = nbase + n * 16 + g * 4;
            u16x4 o;
#pragma unroll
            for (int ri = 0; ri < 4; ++ri) o[ri] = f2b(a1[m][n][ri]);
            *reinterpret_cast<u16x4*>(smem + LDSOFF(r, cb * 2)) = o;
        }
    }
    __syncthreads();
    // scatter plane1 as fragments. Even j run -> pblk 2bi+h, pos-in-block r maps j=64bi+32h+2r;
    // odd j run -> pblk 256+2bi+h, j=64bi+32h+2r+1. (pt=0/8192 dups are never read: dropped.)
    const size_t x1obase = (size_t)b * 512 * 12 * 512;
    for (int idx = tid; idx < 4 * 12 * 64; idx += 512) {
        int q = idx / 768;          // 0..3
        int rem = idx % 768;
        int kb = rem / 64;
        int l2 = rem % 64;
        int h = q & 1, par = q >> 1;
        int r = l2 & 15, g2 = l2 >> 4;
        int jloc = 32 * h + 2 * r + par;
        int ch0 = kb * 32 + g2 * 8;
        uint4 val = *reinterpret_cast<uint4*>(smem + LDSOFF(jloc, ch0 * 2));
        int pblkD = (par ? 256 : 0) + 2 * bi + h;
        *reinterpret_cast<uint4*>(X1out + x1obase + ((size_t)pblkD * 12 + kb) * 512 + l2 * 8) = val;
    }
}

// ---- finalize: out[j] = scan-buffer position (2j+1); plane0 row-major, plane1 fragment
__global__ void finalize(const unsigned short* __restrict__ X0,
                         const unsigned short* __restrict__ X1F, float* __restrict__ out) {
    int idx = blockIdx.x * blockDim.x + threadIdx.x;
    const int total = BATCH * 4096 * 48;
    if (idx >= total) return;
    int dg = idx % 48; int t = idx / 48;
    int j = t % 4096; int b = t / 4096;
    int d0 = dg * 8;
    const unsigned short* s0 = X0 + ((size_t)b * NPOS + (2 * j + 1)) * EMB + d0;
    // pos = 2j+1 -> pblk = j>>3, r = (2j)&15; channels d0..d0+7 = (kb=dg>>2, g2=dg&3)
    int pblk = j >> 3, r = (2 * j) & 15;
    const unsigned short* s1 = X1F + (((size_t)b * 512 + pblk) * 12 + (dg >> 2)) * 512
                                   + ((dg & 3) * 16 + r) * 8;
    size_t o0 = ((size_t)b * 4096 + j) * EMB + d0;
    size_t o1 = o0 + (size_t)BATCH * 4096 * EMB;
    float v0[8], v1[8];
#pragma unroll
    for (int e = 0; e < 8; ++e) { v0[e] = b2f(s0[e]); v1[e] = b2f(s1[e]); }
    *reinterpret_cast<float4*>(out + o0)     = *reinterpret_cast<float4*>(&v0[0]);
    *reinterpret_cast<float4*>(out + o0 + 4) = *reinterpret_cast<float4*>(&v0[4]);
    *reinterpret_cast<float4*>(out + o1)     = *reinterpret_cast<float4*>(&v1[0]);
    *reinterpret_cast<float4*>(out + o1 + 4) = *reinterpret_cast<float4*>(&v1[4]);
}

extern "C" void kernel_launch(void* const* d_in, const int* in_sizes, int n_in,
                              void* d_out, int out_size, void* d_ws, size_t ws_size,
                              hipStream_t stream) {
    const float* embs = (const float*)d_in[0];
    const float* mask = (const float*)d_in[1];
    const float* wl   = (const float*)d_in[2];
    const float* wc   = (const float*)d_in[3];
    const float* wr   = (const float*)d_in[4];
    const float* bias = (const float*)d_in[5];

    const size_t X0E = (size_t)BATCH * NPOS * EMB;        // 12,584,448
    const size_t X1E = (size_t)BATCH * 512 * 12 * 512;    // 12,582,912
    unsigned short* X0A = (unsigned short*)d_ws;
    unsigned short* X0B = X0A + X0E;
    unsigned short* X1A = X0B + X0E;
    unsigned short* X1B = X1A + X1E;
    unsigned short* W   = X1B + X1E;                       // 5,308,416 elems

    {
        int total = LAYERS * 36 * 24 * 64;
        w_prep<<<(total + 255) / 256, 256, 0, stream>>>(wl, wc, wr, W);
    }
    {
        int total = BATCH * NPOS * 48;
        x_init0<<<(total + 255) / 256, 256, 0, stream>>>(embs, mask, X0A);
    }
    {
        int total = BATCH * 512 * 12 * 64;
        x_init1<<<(total + 255) / 256, 256, 0, stream>>>(mask, X1A);
    }
    unsigned short* b0[2] = { X0A, X0B };
    unsigned short* b1[2] = { X1A, X1B };
    for (int l = 0; l < LAYERS; ++l) {
        layer_k<<<dim3(128, BATCH), 512, 0, stream>>>(
            b0[l & 1], b1[l & 1], b0[(l + 1) & 1], b1[(l + 1) & 1],
            W + (size_t)l * 36 * 24 * 64 * 8, bias + (size_t)l * EMB);
    }
    {
        int total = BATCH * 4096 * 48;
        finalize<<<(total + 255) / 256, 256, 0, stream>>>(X0A, X1A, (float*)d_out);
    }
}

// Round 7
// 713.777 us; speedup vs baseline: 1.6939x; 1.6939x over previous
//
#include <hip/hip_runtime.h>
#include <hip/hip_bf16.h>

#define EMB 384
#define NPOS 8193   // 2L+1 state positions
#define LAYERS 12
#define BATCH 4
#define PT 64       // positions per workgroup

typedef __attribute__((ext_vector_type(8))) short bf16x8;
typedef __attribute__((ext_vector_type(4))) float f32x4;
typedef __attribute__((ext_vector_type(4))) unsigned short u16x4;

__device__ __forceinline__ float b2f(unsigned short u) {
    union { unsigned int i; float f; } v; v.i = ((unsigned int)u) << 16; return v.f;
}
__device__ __forceinline__ unsigned short f2b(float f) {
    union { float f; unsigned int i; } v; v.f = f;
    unsigned int x = v.i;
    return (unsigned short)((x + 0x7FFFu + ((x >> 16) & 1u)) >> 16);
}

// LDS tile: 768B rows, XOR bank swizzle (8x16B blocks keyed on row&7)
// rows 0..65  = plane0 pos j0..j0+65 (clamped)
// rows 66..129 = plane1 pos j0+1..j0+64
#define LDSOFF(row, inner) ((row) * 768 + ((inner) ^ (((row) & 7) << 4)))

// ---- weight pre-swizzle: W_swz[layer][kb(36)][nb(24)][lane(64)][8 bf16]
// logical K: 0..383 = w_center, 384..767 = w_right, 768..1151 = w_left
// per 16x32 block: lane holds col n = nb*16 + (lane&15), k = kb*32 + 8*(lane>>4) + e
__global__ void w_prep(const float* __restrict__ wl, const float* __restrict__ wc,
                       const float* __restrict__ wr, unsigned short* __restrict__ wswz) {
    int idx = blockIdx.x * blockDim.x + threadIdx.x;
    const int total = LAYERS * 36 * 24 * 64;
    if (idx >= total) return;
    int lane = idx & 63;
    int t = idx >> 6;
    int nb = t % 24; t /= 24;
    int kb = t % 36; t /= 36;
    int layer = t;
    int seg = kb / 12;
    const float* src = (seg == 0 ? wc : (seg == 1 ? wr : wl)) + (size_t)layer * EMB * EMB;
    int kloc = (kb % 12) * 32 + ((lane >> 4) << 3);
    int n = nb * 16 + (lane & 15);
    unsigned short o[8];
#pragma unroll
    for (int e = 0; e < 8; ++e) o[e] = f2b(src[(size_t)n * EMB + kloc + e]);
    *reinterpret_cast<uint4*>(wswz + (size_t)idx * 8) = *reinterpret_cast<uint4*>(o);
}

// ---- initial state X[b][pos][plane][384] bf16 (interleaved, as in R4)
__global__ void x_init(const float* __restrict__ embs, const float* __restrict__ mask,
                       unsigned short* __restrict__ X) {
    int idx = blockIdx.x * blockDim.x + threadIdx.x;
    const int total = BATCH * NPOS * 48;
    if (idx >= total) return;
    int dg = idx % 48;
    int t = idx / 48;
    int pos = t % NPOS;
    int b = t / NPOS;
    int d0 = dg * 8;
    const float* m = mask + (size_t)b * EMB + d0;
    const float* p0src;
    if (pos >= 1 && pos <= 4096) p0src = embs + ((size_t)b * 4096 + (pos - 1)) * EMB + d0;
    else if (pos == 8192)        p0src = embs + (size_t)b * 4096 * EMB + d0;
    else                         p0src = m;
    unsigned short o0[8], o1[8];
#pragma unroll
    for (int e = 0; e < 8; ++e) { o0[e] = f2b(p0src[e]); o1[e] = f2b(m[e]); }
    size_t base = ((size_t)b * NPOS + pos) * 2 * EMB + d0;
    *reinterpret_cast<uint4*>(X + base)       = *reinterpret_cast<uint4*>(o0);
    *reinterpret_cast<uint4*>(X + base + EMB) = *reinterpret_cast<uint4*>(o1);
}

// ---- one layer, PT=64: 8 waves x (48 cols, 8 m-blocks = 64 pos x 2 planes).
// Both planes in LDS, row-major. Neighbor term plane-independent: computed for
// m=0..3 (plane0), copied to m=4..7. W register double-buffer (2 kb per step).
__global__ __launch_bounds__(512, 2) void layer_k(
    const unsigned short* __restrict__ Xin, unsigned short* __restrict__ Xout,
    const unsigned short* __restrict__ W, const float* __restrict__ bias) {
    __shared__ char smem[130 * 768];
    const int tid = threadIdx.x;
    const int b = blockIdx.y;
    const int j0 = blockIdx.x * PT;
    const size_t xbase = (size_t)b * NPOS * 2 * EMB;

    // stage both planes
    for (int idx = tid; idx < 130 * 48; idx += 512) {
        int row = idx / 48, cg = idx % 48;
        int pos, plane;
        if (row < 66) { pos = j0 + row; if (pos > 8192) pos = 8192; plane = 0; }
        else          { pos = j0 + 1 + (row - 66); plane = 1; }
        uint4 v = *reinterpret_cast<const uint4*>(Xin + xbase + ((size_t)pos * 2 + plane) * EMB + cg * 8);
        *reinterpret_cast<uint4*>(smem + LDSOFF(row, cg * 16)) = v;
    }
    __syncthreads();

    const int lane = tid & 63;
    const int wv = tid >> 6;            // 0..7 n-slice
    const int nbase = wv * 48;
    const int lrow = lane & 15;
    const int g = lane >> 4;

    // center row per m-block: m<4 plane0 (LDS row 16m+lrow+1), m>=4 plane1 (row 66+16(m-4)+lrow)
    int rc[8];
#pragma unroll
    for (int m = 0; m < 8; ++m)
        rc[m] = (m < 4) ? (16 * m + lrow + 1) : (66 + 16 * (m - 4) + lrow);

    f32x4 acc[8][3];
#pragma unroll
    for (int m = 0; m < 4; ++m)
#pragma unroll
        for (int n = 0; n < 3; ++n) acc[m][n] = f32x4{0.f, 0.f, 0.f, 0.f};

    const bf16x8* wb = reinterpret_cast<const bf16x8*>(W) + (size_t)(wv * 3) * 64 + lane;

    bf16x8 wbufA[6], wbufB[6];
#pragma unroll
    for (int n = 0; n < 3; ++n) { wbufA[n] = wb[(12 * 24 + n) * 64]; wbufA[3 + n] = wb[(13 * 24 + n) * 64]; }

    // ---- neighbor phase: kb 12..23 right (x0[p+2]), kb 24..35 left (x0[p]); m=0..3 only
#pragma unroll
    for (int t = 0; t < 12; ++t) {
        bf16x8* cur = (t & 1) ? wbufB : wbufA;
        bf16x8* nxt = (t & 1) ? wbufA : wbufB;
        const int kb0 = 12 + 2 * t;
        const int nk0 = (t < 11) ? kb0 + 2 : 0;   // chain into center kb=0,1
#pragma unroll
        for (int n = 0; n < 3; ++n) { nxt[n] = wb[(nk0 * 24 + n) * 64]; nxt[3 + n] = wb[((nk0 + 1) * 24 + n) * 64]; }
#pragma unroll
        for (int h = 0; h < 2; ++h) {
            const int kb = kb0 + h;
            const int d = (kb < 24) ? 2 : 0;
            const int byo = ((kb - 12) % 12) * 64 + g * 16;
#pragma unroll
            for (int m = 0; m < 4; ++m) {
                const int row = 16 * m + lrow + d;
                bf16x8 xf = *reinterpret_cast<const bf16x8*>(smem + LDSOFF(row, byo));
#pragma unroll
                for (int n = 0; n < 3; ++n)
                    acc[m][n] = __builtin_amdgcn_mfma_f32_16x16x32_bf16(cur[h * 3 + n], xf, acc[m][n], 0, 0, 0);
            }
        }
    }
    // copy plane-independent neighbor result to plane1 accumulators
#pragma unroll
    for (int m = 0; m < 4; ++m)
#pragma unroll
        for (int n = 0; n < 3; ++n) acc[m + 4][n] = acc[m][n];

    // ---- center phase: kb 0..11, all 8 m-blocks
#pragma unroll
    for (int t = 0; t < 6; ++t) {
        bf16x8* cur = (t & 1) ? wbufB : wbufA;
        bf16x8* nxt = (t & 1) ? wbufA : wbufB;
        if (t < 5) {
            const int nk0 = 2 * t + 2;
#pragma unroll
            for (int n = 0; n < 3; ++n) { nxt[n] = wb[(nk0 * 24 + n) * 64]; nxt[3 + n] = wb[((nk0 + 1) * 24 + n) * 64]; }
        }
#pragma unroll
        for (int h = 0; h < 2; ++h) {
            const int byo = (2 * t + h) * 64 + g * 16;
#pragma unroll
            for (int m = 0; m < 8; ++m) {
                bf16x8 xf = *reinterpret_cast<const bf16x8*>(smem + LDSOFF(rc[m], byo));
#pragma unroll
                for (int n = 0; n < 3; ++n)
                    acc[m][n] = __builtin_amdgcn_mfma_f32_16x16x32_bf16(cur[h * 3 + n], xf, acc[m][n], 0, 0, 0);
            }
        }
    }

    // bias: 4 consecutive channels per lane-group
    f32x4 biasv[3];
#pragma unroll
    for (int n = 0; n < 3; ++n)
        biasv[n] = *reinterpret_cast<const f32x4*>(&bias[nbase + n * 16 + (g << 2)]);

    // epilogue: bias + relu + residual (residual from LDS center row, 4 consecutive cols)
#pragma unroll
    for (int m = 0; m < 8; ++m) {
#pragma unroll
        for (int n = 0; n < 3; ++n) {
            const int cb = nbase + n * 16 + (g << 2);
            u16x4 res = *reinterpret_cast<const u16x4*>(smem + LDSOFF(rc[m], cb * 2));
#pragma unroll
            for (int ri = 0; ri < 4; ++ri) {
                float v = acc[m][n][ri] + biasv[n][ri];
                acc[m][n][ri] = fmaxf(v, 0.f) + b2f(res[ri]);
            }
        }
    }
    __syncthreads();
    // out-tile rows 0..127: plane0 -> rows 0..63, plane1 -> rows 64..127
#pragma unroll
    for (int m = 0; m < 8; ++m) {
        const int r = (m < 4) ? (16 * m + lrow) : (64 + 16 * (m - 4) + lrow);
#pragma unroll
        for (int n = 0; n < 3; ++n) {
            const int cb = nbase + n * 16 + (g << 2);
            u16x4 o;
#pragma unroll
            for (int ri = 0; ri < 4; ++ri) o[ri] = f2b(acc[m][n][ri]);
            *reinterpret_cast<u16x4*>(smem + LDSOFF(r, cb * 2)) = o;
        }
    }
    __syncthreads();
    // coalesced scatter with scramble permutation (+ dups at pt 8192 / 0)
    for (int idx = tid; idx < 128 * 48; idx += 512) {
        int rr = idx / 48, cg = idx % 48;
        int plane = rr >> 6, r = rr & 63;
        int j = j0 + r;
        if (j > 8190) continue;
        uint4 val = *reinterpret_cast<uint4*>(smem + LDSOFF(rr, cg * 16));
        int pt = (j & 1) ? ((j + NPOS) >> 1) : ((j >> 1) + 1);
        *reinterpret_cast<uint4*>(Xout + xbase + ((size_t)pt * 2 + plane) * EMB + cg * 8) = val;
        if (j == 0)
            *reinterpret_cast<uint4*>(Xout + xbase + ((size_t)8192 * 2 + plane) * EMB + cg * 8) = val;
        if (j == 8189)
            *reinterpret_cast<uint4*>(Xout + xbase + ((size_t)plane) * EMB + cg * 8) = val;
    }
}

// ---- finalize: 13th scramble composed with slice -> out[j] = scan-buffer position (2j+1)
__global__ void finalize(const unsigned short* __restrict__ X, float* __restrict__ out) {
    int idx = blockIdx.x * blockDim.x + threadIdx.x;
    const int total = BATCH * 4096 * 48;
    if (idx >= total) return;
    int dg = idx % 48; int t = idx / 48;
    int j = t % 4096; int b = t / 4096;
    int d0 = dg * 8;
    size_t src0 = ((size_t)b * NPOS + (2 * j + 1)) * 2 * EMB + d0;
    size_t o0 = ((size_t)b * 4096 + j) * EMB + d0;
    size_t o1 = o0 + (size_t)BATCH * 4096 * EMB;
    float v0[8], v1[8];
#pragma unroll
    for (int e = 0; e < 8; ++e) { v0[e] = b2f(X[src0 + e]); v1[e] = b2f(X[src0 + EMB + e]); }
    *reinterpret_cast<float4*>(out + o0)     = *reinterpret_cast<float4*>(&v0[0]);
    *reinterpret_cast<float4*>(out + o0 + 4) = *reinterpret_cast<float4*>(&v0[4]);
    *reinterpret_cast<float4*>(out + o1)     = *reinterpret_cast<float4*>(&v1[0]);
    *reinterpret_cast<float4*>(out + o1 + 4) = *reinterpret_cast<float4*>(&v1[4]);
}

extern "C" void kernel_launch(void* const* d_in, const int* in_sizes, int n_in,
                              void* d_out, int out_size, void* d_ws, size_t ws_size,
                              hipStream_t stream) {
    const float* embs = (const float*)d_in[0];
    const float* mask = (const float*)d_in[1];
    const float* wl   = (const float*)d_in[2];
    const float* wc   = (const float*)d_in[3];
    const float* wr   = (const float*)d_in[4];
    const float* bias = (const float*)d_in[5];

    const size_t XELEMS = (size_t)BATCH * NPOS * 2 * EMB;    // 25,168,896
    unsigned short* X0 = (unsigned short*)d_ws;
    unsigned short* X1 = X0 + XELEMS;
    unsigned short* W  = X1 + XELEMS;                         // 5,308,416 elems

    {
        int total = LAYERS * 36 * 24 * 64;
        w_prep<<<(total + 255) / 256, 256, 0, stream>>>(wl, wc, wr, W);
    }
    {
        int total = BATCH * NPOS * 48;
        x_init<<<(total + 255) / 256, 256, 0, stream>>>(embs, mask, X0);
    }
    unsigned short* bufs[2] = { X0, X1 };
    for (int l = 0; l < LAYERS; ++l) {
        layer_k<<<dim3(128, BATCH), 512, 0, stream>>>(
            bufs[l & 1], bufs[(l + 1) & 1],
            W + (size_t)l * 36 * 24 * 64 * 8, bias + (size_t)l * EMB);
    }
    {
        int total = BATCH * 4096 * 48;
        finalize<<<(total + 255) / 256, 256, 0, stream>>>(bufs[0], (float*)d_out);
    }
}